// Round 16
// baseline (33.894 us; speedup 1.0000x reference)
//
#include <hip/hip_runtime.h>

#define NTOK 32768
#define NE   1024
#define DD   256

typedef __attribute__((ext_vector_type(4))) float f32x4;

// ---- prep: pmax[b] = max over 16 emb rows of ||e_row||^2  (64 blocks) ----
__global__ __launch_bounds__(256) void prep_norm_kernel(
    const float* __restrict__ emb, float* __restrict__ pmax)
{
    __shared__ float sm[4];
    const int w = threadIdx.x >> 6;
    const int l = threadIdx.x & 63;
    float m = 0.f;
#pragma unroll
    for (int k = 0; k < 4; ++k) {
        const int row = blockIdx.x * 16 + w * 4 + k;
        f32x4 v = *(const f32x4*)(emb + (size_t)row * DD + l * 4);
        float ss = v.x * v.x + v.y * v.y + v.z * v.z + v.w * v.w;
#pragma unroll
        for (int off = 32; off; off >>= 1) ss += __shfl_xor(ss, off, 64);
        m = fmaxf(m, ss);
    }
    if (l == 0) sm[w] = m;
    __syncthreads();
    if (threadIdx.x == 0)
        pmax[blockIdx.x] = fmaxf(fmaxf(sm[0], sm[1]), fmaxf(sm[2], sm[3]));
}

// ---- exact fp32 GEMV + softmax fallback for one non-saturated row ----
// Wave-uniform call. Lane l owns codes l*16..l*16+15, in 4 chunks of 4.
// Overwrites the speculative uniform values (same-wave program order).
__device__ __attribute__((noinline)) void slow_row(
    const float* __restrict__ emb, float* __restrict__ out,
    int row, float ss, f32x4 v, int l)
{
    const int c0 = l * 16;
    float acc[16];
    float s = 0.f;
#pragma unroll
    for (int ch = 0; ch < 4; ++ch) {
        float dot[4] = {0.f, 0.f, 0.f, 0.f};
        float ene[4] = {0.f, 0.f, 0.f, 0.f};
        for (int d4 = 0; d4 < 64; ++d4) {
            f32x4 zz;
            zz.x = __shfl(v.x, d4); zz.y = __shfl(v.y, d4);
            zz.z = __shfl(v.z, d4); zz.w = __shfl(v.w, d4);
#pragma unroll
            for (int c = 0; c < 4; ++c) {
                f32x4 ev = *(const f32x4*)(emb + (size_t)(c0 + ch * 4 + c) * DD + d4 * 4);
                dot[c] = fmaf(zz.x, ev.x, fmaf(zz.y, ev.y,
                         fmaf(zz.z, ev.z, fmaf(zz.w, ev.w, dot[c]))));
                ene[c] = fmaf(ev.x, ev.x, fmaf(ev.y, ev.y,
                         fmaf(ev.z, ev.z, fmaf(ev.w, ev.w, ene[c]))));
            }
        }
#pragma unroll
        for (int c = 0; c < 4; ++c) {
            const float d = ss + ene[c] - 2.0f * dot[c];
            const float u = 10.0f * expf(-10.0f * d);   // u in (0,10]
            const float e = expf(u);
            acc[ch * 4 + c] = e;
            s += e;
        }
    }
#pragma unroll
    for (int off = 32; off; off >>= 1) s += __shfl_xor(s, off, 64);
    const float inv = 1.0f / s;
#pragma unroll
    for (int ch = 0; ch < 4; ++ch) {
        f32x4 o = { acc[ch * 4] * inv, acc[ch * 4 + 1] * inv,
                    acc[ch * 4 + 2] * inv, acc[ch * 4 + 3] * inv };
        *(f32x4*)(out + (size_t)row * NE + c0 + ch * 4) = o;
    }
}

// ---- main: 2 rows/wave, 32-dim partial-norm probe + NT speculative fill ----
// Saturation: FULL ||z_n||^2 >= rhs = (3+E)^2, E = max||e||  =>  d >= 9
// for every code => u = 10*exp(-10d) <= 8e-39 << 2^-53 => exp(u) == 1.0
// exactly in fp32 AND fp64 => softmax row is bit-exactly 1/1024.
// Tier 1: 32-dim partial (lower bound, squares >= 0) >= rhs proves it.
// Tier 2 (rare): full-row norm recheck. Tier 3 (rarer): exact GEMV.
// Exact for ALL inputs.
// A/B vs R15: uniform stores are NON-TEMPORAL (L2 no-allocate) — testing
// whether the fill kernel's 7.07 TB/s vs our 5.3 TB/s is L2 write-allocate.
__global__ __launch_bounds__(256, 8) void sq_main_kernel(
    const float* __restrict__ z, const float* __restrict__ emb,
    const float* __restrict__ pmax, float* __restrict__ out)
{
    const int w  = threadIdx.x >> 6;
    const int l  = threadIdx.x & 63;
    const int r0 = (blockIdx.x * 4 + w) * 2;    // 2 contiguous rows per wave

    // ---- speculative: 8 x 1KB wave-wide NT uniform stores ----
    const float c = 0.0009765625f;   // 1/1024 exactly
    const f32x4 cv = {c, c, c, c};
    float* ob = out + (size_t)r0 * NE + l * 4;
#pragma unroll
    for (int i = 0; i < 8; ++i)
        __builtin_nontemporal_store(cv, (f32x4*)(ob + (size_t)i * 256));

    // ---- probe: half-wave h = l>>5 covers row r0+h, dim l&31 ----
    const float q = z[(size_t)(r0 + (l >> 5)) * DD + (l & 31)];
    float ps = q * q;
#pragma unroll
    for (int off = 1; off < 32; off <<= 1) ps += __shfl_xor(ps, off, 64);

    float m = pmax[l];
#pragma unroll
    for (int off = 32; off; off >>= 1) m = fmaxf(m, __shfl_xor(m, off, 64));
    const float E   = sqrtf(m);
    const float rhs = (3.0f + E) * (3.0f + E);

    if (__builtin_expect(__ballot(ps < rhs) == 0ull, 1)) return;  // proven uniform

    // ---- tier 2: full-norm recheck per row; tier 3: exact overwrite ----
    for (int k = 0; k < 2; ++k) {
        f32x4 v = *(const f32x4*)(z + (size_t)(r0 + k) * DD + l * 4);
        float ss = v.x * v.x + v.y * v.y + v.z * v.z + v.w * v.w;
#pragma unroll
        for (int off = 32; off; off >>= 1) ss += __shfl_xor(ss, off, 64);
        if (ss < rhs) slow_row(emb, out, r0 + k, ss, v, l);
    }
}

extern "C" void kernel_launch(void* const* d_in, const int* in_sizes, int n_in,
                              void* d_out, int out_size, void* d_ws, size_t ws_size,
                              hipStream_t stream) {
    (void)in_sizes; (void)n_in; (void)out_size; (void)ws_size;
    const float* z   = (const float*)d_in[0];
    const float* emb = (const float*)d_in[1];
    float* out = (float*)d_out;
    float* pmax = (float*)d_ws;   // 64 floats

    hipLaunchKernelGGL(prep_norm_kernel, dim3(64), dim3(256), 0, stream,
                       emb, pmax);
    hipLaunchKernelGGL(sq_main_kernel, dim3(NTOK / 8), dim3(256), 0, stream,
                       z, emb, pmax, out);
}

// Round 17
// 30.632 us; speedup vs baseline: 1.1065x; 1.1065x over previous
//
#include <hip/hip_runtime.h>

#define NTOK 32768
#define NE   1024
#define DD   256

typedef __attribute__((ext_vector_type(4))) float f32x4;

// ---- prep: pmax[b] = max over 16 emb rows of ||e_row||^2  (64 blocks) ----
__global__ __launch_bounds__(256) void prep_norm_kernel(
    const float* __restrict__ emb, float* __restrict__ pmax)
{
    __shared__ float sm[4];
    const int w = threadIdx.x >> 6;
    const int l = threadIdx.x & 63;
    float m = 0.f;
#pragma unroll
    for (int k = 0; k < 4; ++k) {
        const int row = blockIdx.x * 16 + w * 4 + k;
        f32x4 v = *(const f32x4*)(emb + (size_t)row * DD + l * 4);
        float ss = v.x * v.x + v.y * v.y + v.z * v.z + v.w * v.w;
#pragma unroll
        for (int off = 32; off; off >>= 1) ss += __shfl_xor(ss, off, 64);
        m = fmaxf(m, ss);
    }
    if (l == 0) sm[w] = m;
    __syncthreads();
    if (threadIdx.x == 0)
        pmax[blockIdx.x] = fmaxf(fmaxf(sm[0], sm[1]), fmaxf(sm[2], sm[3]));
}

// ---- exact fp32 GEMV + softmax fallback for one non-saturated row ----
// Wave-uniform call. Lane l owns codes l*16..l*16+15, in 4 chunks of 4.
// Overwrites the speculative uniform values (same-wave program order).
__device__ __attribute__((noinline)) void slow_row(
    const float* __restrict__ emb, float* __restrict__ out,
    int row, float ss, f32x4 v, int l)
{
    const int c0 = l * 16;
    float acc[16];
    float s = 0.f;
#pragma unroll
    for (int ch = 0; ch < 4; ++ch) {
        float dot[4] = {0.f, 0.f, 0.f, 0.f};
        float ene[4] = {0.f, 0.f, 0.f, 0.f};
        for (int d4 = 0; d4 < 64; ++d4) {
            f32x4 zz;
            zz.x = __shfl(v.x, d4); zz.y = __shfl(v.y, d4);
            zz.z = __shfl(v.z, d4); zz.w = __shfl(v.w, d4);
#pragma unroll
            for (int c = 0; c < 4; ++c) {
                f32x4 ev = *(const f32x4*)(emb + (size_t)(c0 + ch * 4 + c) * DD + d4 * 4);
                dot[c] = fmaf(zz.x, ev.x, fmaf(zz.y, ev.y,
                         fmaf(zz.z, ev.z, fmaf(zz.w, ev.w, dot[c]))));
                ene[c] = fmaf(ev.x, ev.x, fmaf(ev.y, ev.y,
                         fmaf(ev.z, ev.z, fmaf(ev.w, ev.w, ene[c]))));
            }
        }
#pragma unroll
        for (int c = 0; c < 4; ++c) {
            const float d = ss + ene[c] - 2.0f * dot[c];
            const float u = 10.0f * expf(-10.0f * d);   // u in (0,10]
            const float e = expf(u);
            acc[ch * 4 + c] = e;
            s += e;
        }
    }
#pragma unroll
    for (int off = 32; off; off >>= 1) s += __shfl_xor(s, off, 64);
    const float inv = 1.0f / s;
#pragma unroll
    for (int ch = 0; ch < 4; ++ch) {
        f32x4 o = { acc[ch * 4] * inv, acc[ch * 4 + 1] * inv,
                    acc[ch * 4 + 2] * inv, acc[ch * 4 + 3] * inv };
        *(f32x4*)(out + (size_t)row * NE + c0 + ch * 4) = o;
    }
}

// ---- main: 2 rows/wave, 32-dim partial-norm probe + speculative fill ----
// Saturation: FULL ||z_n||^2 >= rhs = (3+E)^2, E = max||e||  =>  d >= 9
// for every code => u = 10*exp(-10d) <= 8e-39 << 2^-53 => exp(u) == 1.0
// exactly in fp32 AND fp64 => softmax row is bit-exactly 1/1024.
// Tier 1: 32-dim partial (lower bound, squares >= 0) >= rhs proves it.
// Tier 2 (rare): full-row norm recheck. Tier 3 (rarer): exact GEMV.
// Exact for ALL inputs. Plain stores (R16 A/B: NT stores −3 µs on gfx950).
__global__ __launch_bounds__(256, 8) void sq_main_kernel(
    const float* __restrict__ z, const float* __restrict__ emb,
    const float* __restrict__ pmax, float* __restrict__ out)
{
    const int w  = threadIdx.x >> 6;
    const int l  = threadIdx.x & 63;
    const int r0 = (blockIdx.x * 4 + w) * 2;    // 2 contiguous rows per wave

    // ---- speculative: 8 x 1KB wave-wide uniform stores (depend on nothing) ----
    const float c = 0.0009765625f;   // 1/1024 exactly
    const f32x4 cv = {c, c, c, c};
    float* ob = out + (size_t)r0 * NE + l * 4;
#pragma unroll
    for (int i = 0; i < 8; ++i)
        *(f32x4*)(ob + (size_t)i * 256) = cv;

    // ---- probe: half-wave h = l>>5 covers row r0+h, dim l&31 ----
    const float q = z[(size_t)(r0 + (l >> 5)) * DD + (l & 31)];
    float ps = q * q;
#pragma unroll
    for (int off = 1; off < 32; off <<= 1) ps += __shfl_xor(ps, off, 64);

    float m = pmax[l];
#pragma unroll
    for (int off = 32; off; off >>= 1) m = fmaxf(m, __shfl_xor(m, off, 64));
    const float E   = sqrtf(m);
    const float rhs = (3.0f + E) * (3.0f + E);

    if (__builtin_expect(__ballot(ps < rhs) == 0ull, 1)) return;  // proven uniform

    // ---- tier 2: full-norm recheck per row; tier 3: exact overwrite ----
    for (int k = 0; k < 2; ++k) {
        f32x4 v = *(const f32x4*)(z + (size_t)(r0 + k) * DD + l * 4);
        float ss = v.x * v.x + v.y * v.y + v.z * v.z + v.w * v.w;
#pragma unroll
        for (int off = 32; off; off >>= 1) ss += __shfl_xor(ss, off, 64);
        if (ss < rhs) slow_row(emb, out, r0 + k, ss, v, l);
    }
}

extern "C" void kernel_launch(void* const* d_in, const int* in_sizes, int n_in,
                              void* d_out, int out_size, void* d_ws, size_t ws_size,
                              hipStream_t stream) {
    (void)in_sizes; (void)n_in; (void)out_size; (void)ws_size;
    const float* z   = (const float*)d_in[0];
    const float* emb = (const float*)d_in[1];
    float* out = (float*)d_out;
    float* pmax = (float*)d_ws;   // 64 floats

    hipLaunchKernelGGL(prep_norm_kernel, dim3(64), dim3(256), 0, stream,
                       emb, pmax);
    hipLaunchKernelGGL(sq_main_kernel, dim3(NTOK / 8), dim3(256), 0, stream,
                       z, emb, pmax, out);
}